// Round 2
// baseline (1312.746 us; speedup 1.0000x reference)
//
#include <hip/hip_runtime.h>
#include <hip/hip_bf16.h>

#define NN   4096
#define KNEI 16
#define NPB  8              // nodes (waves) per block
#define BLOCK (NPB * 64)

__global__ __launch_bounds__(BLOCK)
void protein_enc_kernel(const float* __restrict__ coords,
                        const int*   __restrict__ atypes,
                        const int*   __restrict__ rtypes,
                        const float* __restrict__ tpw,
                        const float* __restrict__ aemb,
                        const float* __restrict__ remb,
                        float* __restrict__ out)
{
    __shared__ float4 pts[NN];      // x, y, z, n2
    __shared__ float  sW[8 * 32];

    const int tid  = threadIdx.x;
    const int lane = tid & 63;
    const int wv   = tid >> 6;
    const int bpb  = NN / NPB;                     // blocks per batch
    const int batch    = blockIdx.x / bpb;
    const int nodeBase = (blockIdx.x % bpb) * NPB;

    const float* cb = coords + (size_t)batch * NN * 3;

    // ---- stage coords + squared norms into LDS (exact-rounded, no FMA) ----
    for (int p = tid; p < NN; p += BLOCK) {
        float x = cb[3*p], y = cb[3*p+1], z = cb[3*p+2];
        float n2 = __fadd_rn(__fadd_rn(__fmul_rn(x,x), __fmul_rn(y,y)), __fmul_rn(z,z));
        pts[p] = make_float4(x, y, z, n2);
    }
    if (tid < 256) sW[tid] = tpw[tid];
    __syncthreads();

    const int iLoc = nodeBase + wv;
    const int gi   = batch * NN + iLoc;
    const float4 Pi = pts[iLoc];
    const float xi = Pi.x, yi = Pi.y, zi = Pi.z, n2i = Pi.w;

    // ---- per-lane sorted top-16 over this lane's 64 candidates ----
    float kd[KNEI];
    int   ki[KNEI];
    #pragma unroll
    for (int t = 0; t < KNEI; ++t) { kd[t] = 3.0e38f; ki[t] = 0x7fffffff; }

    float T = 3.0e38f;               // wave-shared prune threshold
    int j = lane;
    for (int c = 0; c < NN / 64; ++c, j += 64) {
        float4 P = pts[j];
        float dot = __fadd_rn(__fadd_rn(__fmul_rn(xi, P.x), __fmul_rn(yi, P.y)),
                              __fmul_rn(zi, P.z));
        float d2  = __fsub_rn(__fadd_rn(n2i, P.w), __fmul_rn(2.0f, dot));
        if (j == iLoc) d2 = 1.0e30f;                 // exclude self
        if (d2 <= T && d2 < kd[KNEI-1]) {            // <=T keeps boundary ties
            kd[KNEI-1] = d2; ki[KNEI-1] = j;
            #pragma unroll
            for (int t = KNEI-1; t > 0; --t) {
                if (kd[t] >= kd[t-1]) break;         // stable: equal keeps order
                float tf = kd[t]; kd[t] = kd[t-1]; kd[t-1] = tf;
                int   ti = ki[t]; ki[t] = ki[t-1]; ki[t-1] = ti;
            }
        }
        if ((c & 7) == 7) {                          // refresh prune threshold
            float tt = kd[KNEI-1];
            #pragma unroll
            for (int off = 32; off >= 1; off >>= 1)
                tt = fminf(tt, __shfl_xor(tt, off));
            T = tt;
        }
    }

    // ---- merge: 16 rounds of wave-wide lexicographic argmin + pop ----
    // (lane l only ever holds indices j ≡ l mod 64, so (key,idx) pairs are
    //  lane-disjoint and exactly one lane pops per round)
    int selIdx = 0;
    float hk = kd[0]; int hi = ki[0];
    #pragma unroll 1
    for (int r = 0; r < KNEI; ++r) {
        float mk = hk; int mi = hi;
        #pragma unroll
        for (int off = 32; off >= 1; off >>= 1) {
            float ok = __shfl_xor(mk, off);
            int   oi = __shfl_xor(mi, off);
            if (ok < mk || (ok == mk && oi < mi)) { mk = ok; mi = oi; }
        }
        if (lane == r) selIdx = mi;                  // lane r owns neighbor r
        if (hk == mk && hi == mi) {                  // winner pops its head
            #pragma unroll
            for (int t = 0; t < KNEI-1; ++t) { kd[t] = kd[t+1]; ki[t] = ki[t+1]; }
            kd[KNEI-1] = 3.0e38f; ki[KNEI-1] = 0x7fffffff;
            hk = kd[0]; hi = ki[0];
        }
    }

    // ---- per-edge radial basis x direction, S[v][m] = sum_e rb_e[v]*rhat_e[m] ----
    float S[24];
    #pragma unroll
    for (int t = 0; t < 24; ++t) S[t] = 0.0f;
    if (lane < KNEI) {
        float4 P = pts[selIdx];
        float rx = P.x - xi, ry = P.y - yi, rz = P.z - zi;   // sender - receiver
        float dist = sqrtf(rx*rx + ry*ry + rz*rz);
        float inv  = 1.0f / (dist + 1e-8f);
        float hx = rx * inv, hy = ry * inv, hz = rz * inv;
        float cu = fminf(dist / 10.0f, 1.0f);
        const float centers[8] = {0.0f, (float)(1.0/7.0), (float)(2.0/7.0),
                                  (float)(3.0/7.0), (float)(4.0/7.0),
                                  (float)(5.0/7.0), (float)(6.0/7.0), 1.0f};
        float g[8], s = 0.0f;
        #pragma unroll
        for (int v = 0; v < 8; ++v) {
            float d = cu - centers[v];
            g[v] = expf(d * d * -32.0f);             // exp(-(d^2)/(2*(1/8)^2))
            s += g[v];
        }
        float is = 1.0f / s;
        #pragma unroll
        for (int v = 0; v < 8; ++v) {
            float r = g[v] * is;
            S[3*v]   = r * hx;
            S[3*v+1] = r * hy;
            S[3*v+2] = r * hz;
        }
    }
    #pragma unroll
    for (int off = 1; off <= 32; off <<= 1) {
        #pragma unroll
        for (int t = 0; t < 24; ++t) S[t] += __shfl_xor(S[t], off);
    }

    // ---- epilogue: node row is 464 f32 = 116 float4, base 16B-aligned ----
    float* onode = out + (size_t)gi * 464;
    float4* o4 = (float4*)onode;
    const float4 z4 = make_float4(0.f, 0.f, 0.f, 0.f);

    // zeros: ch 0..63 -> o4[0..15]; ch 160..239 -> o4[40..59]
    if (lane < 16)       o4[lane] = z4;
    else if (lane < 36)  o4[lane + 24] = z4;

    // out[w][m] = scale * sum_v W[v][w] * S[v][m] ; channels 64..159
    const float scale = 0.036084391824351613f;       // 1/(16*sqrt(3))
    if (lane < 32) {
        int w = lane;
        float a0 = 0.f, a1 = 0.f, a2 = 0.f;
        #pragma unroll
        for (int v = 0; v < 8; ++v) {
            float wf = sW[32*v + w];
            a0 += wf * S[3*v];
            a1 += wf * S[3*v+1];
            a2 += wf * S[3*v+2];
        }
        onode[64 + 3*w]     = a0 * scale;
        onode[64 + 3*w + 1] = a1 * scale;
        onode[64 + 3*w + 2] = a2 * scale;
    }

    // embeddings: ch 240..463 -> o4[60..115] (both tables 112 f32 = 28 float4/row)
    const int at = atypes[gi];
    const int rt = rtypes[gi];
    if (lane < 56) {
        float4 v = (lane < 28)
            ? ((const float4*)(aemb + 112*at))[lane]
            : ((const float4*)(remb + 112*rt))[lane - 28];
        o4[60 + lane] = v;
    }
}

extern "C" void kernel_launch(void* const* d_in, const int* in_sizes, int n_in,
                              void* d_out, int out_size, void* d_ws, size_t ws_size,
                              hipStream_t stream)
{
    const float* coords = (const float*)d_in[0];
    const int*   at     = (const int*)  d_in[1];
    const int*   rt     = (const int*)  d_in[2];
    const float* tpw    = (const float*)d_in[3];
    const float* ae     = (const float*)d_in[4];
    const float* re     = (const float*)d_in[5];
    float* out = (float*)d_out;

    const int B = in_sizes[1] / NN;                  // 8
    dim3 grid(B * (NN / NPB));
    protein_enc_kernel<<<grid, BLOCK, 0, stream>>>(coords, at, rt, tpw, ae, re, out);
}

// Round 3
// 133.809 us; speedup vs baseline: 9.8106x; 9.8106x over previous
//
#include <hip/hip_runtime.h>
#include <hip/hip_bf16.h>

#define NN   4096
#define KNEI 16
#define NPB  8              // nodes (waves) per block
#define BLOCK (NPB * 64)
#define BIGF 3.0e38f

__device__ __forceinline__ float d2_calc(const float4 P, float xi, float yi,
                                         float zi, float n2i, int j, int iLoc)
{
    float dot = __fadd_rn(__fadd_rn(__fmul_rn(xi, P.x), __fmul_rn(yi, P.y)),
                          __fmul_rn(zi, P.z));
    float d2  = __fsub_rn(__fadd_rn(n2i, P.w), __fmul_rn(2.0f, dot));
    return (j == iLoc) ? 1.0e30f : d2;
}

// Wave-wide argmin of (v, idx) with exact lowest-index tie-break.
// All lanes receive m (min value), midx (its index); w = owning lane (uniform).
__device__ __forceinline__ void wave_argmin(float v, int idx,
                                            float& m, int& midx, int& w)
{
    float r = v;
    #pragma unroll
    for (int off = 32; off >= 1; off >>= 1) r = fminf(r, __shfl_xor(r, off));
    unsigned long long msk = __ballot(v == r);
    if (__popcll(msk) > 1) {                      // rare exact tie: lowest index
        int ci = (v == r) ? idx : 0x7fffffff;
        #pragma unroll
        for (int off = 32; off >= 1; off >>= 1) ci = min(ci, __shfl_xor(ci, off));
        midx = ci;
        unsigned long long m2 = __ballot(v == r && idx == ci);
        w = __ffsll(m2) - 1;
    } else {
        w = __ffsll(msk) - 1;
        midx = __builtin_amdgcn_readlane(idx, w);
    }
    m = r;
}

__global__ __launch_bounds__(BLOCK)
void protein_enc_kernel(const float* __restrict__ coords,
                        const int*   __restrict__ atypes,
                        const int*   __restrict__ rtypes,
                        const float* __restrict__ tpw,
                        const float* __restrict__ aemb,
                        const float* __restrict__ remb,
                        float* __restrict__ out)
{
    __shared__ float4 pts[NN];      // x, y, z, n2
    __shared__ float  sW[8 * 32];

    const int tid  = threadIdx.x;
    const int lane = tid & 63;
    const int wv   = tid >> 6;
    const int bpb  = NN / NPB;
    const int batch    = blockIdx.x / bpb;
    const int nodeBase = (blockIdx.x % bpb) * NPB;

    const float* cb = coords + (size_t)batch * NN * 3;

    for (int p = tid; p < NN; p += BLOCK) {
        float x = cb[3*p], y = cb[3*p+1], z = cb[3*p+2];
        float n2 = __fadd_rn(__fadd_rn(__fmul_rn(x,x), __fmul_rn(y,y)), __fmul_rn(z,z));
        pts[p] = make_float4(x, y, z, n2);
    }
    if (tid < 256) sW[tid] = tpw[tid];
    __syncthreads();

    const int iLoc = nodeBase + wv;
    const int gi   = batch * NN + iLoc;
    const float4 Pi = pts[iLoc];
    const float xi = Pi.x, yi = Pi.y, zi = Pi.z, n2i = Pi.w;

    // ---- phase 1: branchless per-lane top-2 over 64 candidates ----
    float b_d2 = BIGF, s_d2 = BIGF;
    int   b_idx = -1,  s_idx = -1;

    #pragma unroll 8
    for (int c = 0; c < NN / 64; ++c) {
        int j = lane + (c << 6);
        float d2 = d2_calc(pts[j], xi, yi, zi, n2i, j, iLoc);
        bool lt_b = d2 < b_d2;
        bool lt_s = d2 < s_d2;
        // shift-insert into the 2-slot ladder, stable on ties (strict <)
        float ns_d2 = lt_b ? b_d2 : (lt_s ? d2 : s_d2);
        int   ns_i  = lt_b ? b_idx : (lt_s ? j : s_idx);
        b_d2  = lt_b ? d2 : b_d2;
        b_idx = lt_b ? j  : b_idx;
        s_d2  = ns_d2;
        s_idx = ns_i;
    }

    // ---- phase 2: 16 extractions with lazy replay ----
    unsigned long long used = 0ull;   // bit t => candidate (lane + 64t) consumed
    int selIdx = 0;

    #pragma unroll 1
    for (int r = 0; r < KNEI; ++r) {
        float m; int midx, w;
        wave_argmin(b_d2, b_idx, m, midx, w);
        if ((lane >> 2) == r) selIdx = midx;          // 4-lane team r owns edge r

        bool needReplay = (__builtin_amdgcn_readlane(s_idx, w) == -1);
        if (lane == w) {                               // promote second -> best
            used |= 1ull << (b_idx >> 6);
            b_d2 = s_d2;  b_idx = s_idx;
            s_d2 = BIGF;  s_idx = -1;
        }
        if (needReplay) {                              // uniform rare branch:
            int j2 = w + (lane << 6);                  // wave rescans lane w's 64
            float d2r = d2_calc(pts[j2], xi, yi, zi, n2i, j2, iLoc);
            unsigned lo = (unsigned)__builtin_amdgcn_readlane((int)(used & 0xffffffffull), w);
            unsigned hi = (unsigned)__builtin_amdgcn_readlane((int)(used >> 32), w);
            unsigned long long uw = ((unsigned long long)hi << 32) | lo;
            if ((uw >> lane) & 1ull) d2r = BIGF;
            float m2; int i2, w2;
            wave_argmin(d2r, j2, m2, i2, w2);
            if (lane == w) { b_d2 = m2; b_idx = i2; }  // refill best only
        }
    }

    // ---- epilogue: 4 lanes per edge, 6 S-components each ----
    const int g = lane & 3;                // component group within the team
    float4 P = pts[selIdx];
    float rx = P.x - xi, ry = P.y - yi, rz = P.z - zi;   // sender - receiver
    float dist = sqrtf(rx*rx + ry*ry + rz*rz);
    float inv  = 1.0f / (dist + 1e-8f);
    float hx = rx * inv, hy = ry * inv, hz = rz * inv;
    float cu = fminf(dist / 10.0f, 1.0f);
    float gg[8], ssum = 0.0f;
    #pragma unroll
    for (int v = 0; v < 8; ++v) {
        float d = cu - (float)v * (1.0f / 7.0f);
        gg[v] = expf(d * d * -32.0f);
        ssum += gg[v];
    }
    float is = 1.0f / ssum;
    float rb0 = gg[2*g] * is, rb1 = gg[2*g+1] * is;
    float S[6] = { rb0*hx, rb0*hy, rb0*hz, rb1*hx, rb1*hy, rb1*hz };

    #pragma unroll
    for (int off = 4; off <= 32; off <<= 1) {
        #pragma unroll
        for (int t = 0; t < 6; ++t) S[t] += __shfl_xor(S[t], off);
    }
    // lanes 0..3 now hold the 24 edge-summed components; publish uniformly
    float sg[24];
    #pragma unroll
    for (int g0 = 0; g0 < 4; ++g0) {
        #pragma unroll
        for (int t = 0; t < 6; ++t)
            sg[6*g0 + t] = __int_as_float(
                __builtin_amdgcn_readlane(__float_as_int(S[t]), g0));
    }

    float* onode = out + (size_t)gi * 464;
    float4* o4 = (float4*)onode;
    const float4 z4 = make_float4(0.f, 0.f, 0.f, 0.f);
    if (lane < 16)       o4[lane] = z4;          // ch 0..63
    else if (lane < 36)  o4[lane + 24] = z4;     // ch 160..239

    const float scale = 0.036084391824351613f;   // 1/(16*sqrt(3))
    if (lane < 32) {
        float a0 = 0.f, a1 = 0.f, a2 = 0.f;
        #pragma unroll
        for (int v = 0; v < 8; ++v) {
            float wf = sW[32*v + lane];
            a0 = fmaf(wf, sg[3*v],   a0);
            a1 = fmaf(wf, sg[3*v+1], a1);
            a2 = fmaf(wf, sg[3*v+2], a2);
        }
        onode[64 + 3*lane]     = a0 * scale;
        onode[64 + 3*lane + 1] = a1 * scale;
        onode[64 + 3*lane + 2] = a2 * scale;
    }

    const int at = atypes[gi];
    const int rt = rtypes[gi];
    if (lane < 56) {
        float4 v = (lane < 28)
            ? ((const float4*)(aemb + 112*at))[lane]
            : ((const float4*)(remb + 112*rt))[lane - 28];
        o4[60 + lane] = v;
    }
}

extern "C" void kernel_launch(void* const* d_in, const int* in_sizes, int n_in,
                              void* d_out, int out_size, void* d_ws, size_t ws_size,
                              hipStream_t stream)
{
    const float* coords = (const float*)d_in[0];
    const int*   at     = (const int*)  d_in[1];
    const int*   rt     = (const int*)  d_in[2];
    const float* tpw    = (const float*)d_in[3];
    const float* ae     = (const float*)d_in[4];
    const float* re     = (const float*)d_in[5];
    float* out = (float*)d_out;

    const int B = in_sizes[1] / NN;                  // 8
    dim3 grid(B * (NN / NPB));
    protein_enc_kernel<<<grid, BLOCK, 0, stream>>>(coords, at, rt, tpw, ae, re, out);
}

// Round 4
// 108.649 us; speedup vs baseline: 12.0825x; 1.2316x over previous
//
#include <hip/hip_runtime.h>
#include <hip/hip_bf16.h>

#define NN   4096
#define KNEI 16
#define NPB  16             // nodes (waves) per block
#define BLOCK (NPB * 64)
#define BIGF 3.0e38f

__device__ __forceinline__ float d2_calc(const float4 P, float xi, float yi,
                                         float zi, float n2i, int j, int iLoc)
{
    float dot = __fadd_rn(__fadd_rn(__fmul_rn(xi, P.x), __fmul_rn(yi, P.y)),
                          __fmul_rn(zi, P.z));
    float d2  = __fsub_rn(__fadd_rn(n2i, P.w), __fmul_rn(2.0f, dot));
    return (j == iLoc) ? 1.0e30f : d2;
}

// Wave-wide argmin of (v, idx) with exact lowest-index tie-break.
__device__ __forceinline__ void wave_argmin(float v, int idx,
                                            float& m, int& midx, int& w)
{
    float r = v;
    #pragma unroll
    for (int off = 32; off >= 1; off >>= 1) r = fminf(r, __shfl_xor(r, off));
    unsigned long long msk = __ballot(v == r);
    if (__popcll(msk) > 1) {                      // rare exact tie: lowest index
        int ci = (v == r) ? idx : 0x7fffffff;
        #pragma unroll
        for (int off = 32; off >= 1; off >>= 1) ci = min(ci, __shfl_xor(ci, off));
        midx = ci;
        unsigned long long m2 = __ballot(v == r && idx == ci);
        w = __ffsll(m2) - 1;
    } else {
        w = __ffsll(msk) - 1;
        midx = __builtin_amdgcn_readlane(idx, w);
    }
    m = r;
}

__global__ __launch_bounds__(BLOCK)
void protein_enc_kernel(const float* __restrict__ coords,
                        const int*   __restrict__ atypes,
                        const int*   __restrict__ rtypes,
                        const float* __restrict__ tpw,
                        const float* __restrict__ aemb,
                        const float* __restrict__ remb,
                        float* __restrict__ out)
{
    __shared__ float4 pts[NN];      // x, y, z, n2
    __shared__ float  sW[8 * 32];

    const int tid  = threadIdx.x;
    const int lane = tid & 63;
    const int wv   = tid >> 6;
    const int bpb  = NN / NPB;
    const int batch    = blockIdx.x / bpb;
    const int nodeBase = (blockIdx.x % bpb) * NPB;

    const float* cb = coords + (size_t)batch * NN * 3;

    for (int p = tid; p < NN; p += BLOCK) {
        float x = cb[3*p], y = cb[3*p+1], z = cb[3*p+2];
        float n2 = __fadd_rn(__fadd_rn(__fmul_rn(x,x), __fmul_rn(y,y)), __fmul_rn(z,z));
        pts[p] = make_float4(x, y, z, n2);
    }
    if (tid < 256) sW[tid] = tpw[tid];
    __syncthreads();

    const int iLoc = nodeBase + wv;
    const int gi   = batch * NN + iLoc;
    const float4 Pi = pts[iLoc];
    const float xi = Pi.x, yi = Pi.y, zi = Pi.z, n2i = Pi.w;

    // ---- phase 1: branchless per-lane top-2 (no self-check in hot loop) ----
    float b_d2 = BIGF, s_d2 = BIGF;
    int   b_idx = -1,  s_idx = -1;

    #pragma unroll 8
    for (int c = 0; c < NN / 64; ++c) {
        int j = lane + (c << 6);
        float4 P = pts[j];
        float dot = __fadd_rn(__fadd_rn(__fmul_rn(xi, P.x), __fmul_rn(yi, P.y)),
                              __fmul_rn(zi, P.z));
        float d2  = __fsub_rn(__fadd_rn(n2i, P.w), __fmul_rn(2.0f, dot));
        bool lt_b = d2 < b_d2;
        bool lt_s = d2 < s_d2;
        float m1 = fmaxf(b_d2, d2);
        s_d2  = fminf(s_d2, m1);
        s_idx = lt_b ? b_idx : (lt_s ? j : s_idx);
        b_d2  = fminf(b_d2, d2);
        b_idx = lt_b ? j : b_idx;
    }

    // self lands as its column's best (|self d2| <= ~7e-4 << any true d2): drop it
    if (lane == (iLoc & 63) && b_idx == iLoc) {
        b_d2 = s_d2; b_idx = s_idx; s_d2 = BIGF; s_idx = -1;
    }

    // ---- phase 2: 16 extractions with lazy replay ----
    unsigned long long used = 0ull;   // bit t => candidate (lane + 64t) consumed
    int selIdx = 0;

    #pragma unroll 1
    for (int r = 0; r < KNEI; ++r) {
        float m; int midx, w;
        wave_argmin(b_d2, b_idx, m, midx, w);
        if ((lane >> 2) == r) selIdx = midx;          // 4-lane team r owns edge r

        bool needReplay = (__builtin_amdgcn_readlane(s_idx, w) == -1);
        if (lane == w) {                               // promote second -> best
            used |= 1ull << (b_idx >> 6);
            b_d2 = s_d2;  b_idx = s_idx;
            s_d2 = BIGF;  s_idx = -1;
        }
        if (needReplay) {                              // uniform rare branch:
            int j2 = w + (lane << 6);                  // wave rescans lane w's 64
            float d2r = d2_calc(pts[j2], xi, yi, zi, n2i, j2, iLoc);
            unsigned lo = (unsigned)__builtin_amdgcn_readlane((int)(used & 0xffffffffull), w);
            unsigned hi = (unsigned)__builtin_amdgcn_readlane((int)(used >> 32), w);
            unsigned long long uw = ((unsigned long long)hi << 32) | lo;
            if ((uw >> lane) & 1ull) d2r = BIGF;
            float m2; int i2, w2;
            wave_argmin(d2r, j2, m2, i2, w2);
            if (lane == w) { b_d2 = m2; b_idx = i2; }  // refill best only
        }
    }

    // ---- epilogue: 4 lanes per edge, 6 S-components each ----
    const int g = lane & 3;                // component group within the team
    float4 P = pts[selIdx];
    float rx = P.x - xi, ry = P.y - yi, rz = P.z - zi;   // sender - receiver
    float dist = sqrtf(rx*rx + ry*ry + rz*rz);
    float inv  = 1.0f / (dist + 1e-8f);
    float hx = rx * inv, hy = ry * inv, hz = rz * inv;
    float cu = fminf(dist / 10.0f, 1.0f);
    float gg[8], ssum = 0.0f;
    #pragma unroll
    for (int v = 0; v < 8; ++v) {
        float d = cu - (float)v * (1.0f / 7.0f);
        gg[v] = expf(d * d * -32.0f);
        ssum += gg[v];
    }
    float is = 1.0f / ssum;
    float rb0 = gg[2*g] * is, rb1 = gg[2*g+1] * is;
    float S[6] = { rb0*hx, rb0*hy, rb0*hz, rb1*hx, rb1*hy, rb1*hz };

    #pragma unroll
    for (int off = 4; off <= 32; off <<= 1) {
        #pragma unroll
        for (int t = 0; t < 6; ++t) S[t] += __shfl_xor(S[t], off);
    }
    // lanes 0..3 now hold the 24 edge-summed components; publish uniformly
    float sg[24];
    #pragma unroll
    for (int g0 = 0; g0 < 4; ++g0) {
        #pragma unroll
        for (int t = 0; t < 6; ++t)
            sg[6*g0 + t] = __int_as_float(
                __builtin_amdgcn_readlane(__float_as_int(S[t]), g0));
    }

    float* onode = out + (size_t)gi * 464;
    float4* o4 = (float4*)onode;
    const float4 z4 = make_float4(0.f, 0.f, 0.f, 0.f);
    if (lane < 16)       o4[lane] = z4;          // ch 0..63
    else if (lane < 36)  o4[lane + 24] = z4;     // ch 160..239

    const float scale = 0.036084391824351613f;   // 1/(16*sqrt(3))
    if (lane < 32) {
        float a0 = 0.f, a1 = 0.f, a2 = 0.f;
        #pragma unroll
        for (int v = 0; v < 8; ++v) {
            float wf = sW[32*v + lane];
            a0 = fmaf(wf, sg[3*v],   a0);
            a1 = fmaf(wf, sg[3*v+1], a1);
            a2 = fmaf(wf, sg[3*v+2], a2);
        }
        onode[64 + 3*lane]     = a0 * scale;
        onode[64 + 3*lane + 1] = a1 * scale;
        onode[64 + 3*lane + 2] = a2 * scale;
    }

    const int at = atypes[gi];
    const int rt = rtypes[gi];
    if (lane < 56) {
        float4 v = (lane < 28)
            ? ((const float4*)(aemb + 112*at))[lane]
            : ((const float4*)(remb + 112*rt))[lane - 28];
        o4[60 + lane] = v;
    }
}

extern "C" void kernel_launch(void* const* d_in, const int* in_sizes, int n_in,
                              void* d_out, int out_size, void* d_ws, size_t ws_size,
                              hipStream_t stream)
{
    const float* coords = (const float*)d_in[0];
    const int*   at     = (const int*)  d_in[1];
    const int*   rt     = (const int*)  d_in[2];
    const float* tpw    = (const float*)d_in[3];
    const float* ae     = (const float*)d_in[4];
    const float* re     = (const float*)d_in[5];
    float* out = (float*)d_out;

    const int B = in_sizes[1] / NN;                  // 8
    dim3 grid(B * (NN / NPB));
    protein_enc_kernel<<<grid, BLOCK, 0, stream>>>(coords, at, rt, tpw, ae, re, out);
}

// Round 5
// 95.149 us; speedup vs baseline: 13.7967x; 1.1419x over previous
//
#include <hip/hip_runtime.h>
#include <hip/hip_bf16.h>

#define NN   4096
#define KNEI 16
#define NPB  16             // nodes (waves) per block
#define BLOCK (NPB * 64)
#define BIGF 3.0e38f

// surrogate score: larger == closer.  pts[j] = (x, y, z, -n2/2)
__device__ __forceinline__ float score_calc(const float4 P, float xi, float yi,
                                            float zi, int j, int iLoc)
{
    float s = fmaf(P.x, xi, fmaf(P.y, yi, fmaf(P.z, zi, P.w)));
    return (j == iLoc) ? -1.0e30f : s;
}

// Wave-wide argmax of (v, idx), ties -> lowest idx (matches stable top_k).
__device__ __forceinline__ void wave_argmax(float v, int idx,
                                            float& m, int& midx, int& w)
{
    float r = v;
    #pragma unroll
    for (int off = 32; off >= 1; off >>= 1) r = fmaxf(r, __shfl_xor(r, off));
    unsigned long long msk = __ballot(v == r);
    if (__popcll(msk) > 1) {                      // rare exact tie: lowest index
        int ci = (v == r) ? idx : 0x7fffffff;
        #pragma unroll
        for (int off = 32; off >= 1; off >>= 1) ci = min(ci, __shfl_xor(ci, off));
        midx = ci;
        unsigned long long m2 = __ballot(v == r && idx == ci);
        w = __ffsll(m2) - 1;
    } else {
        w = __ffsll(msk) - 1;
        midx = __builtin_amdgcn_readlane(idx, w);
    }
    m = r;
}

__global__ __launch_bounds__(BLOCK)
void protein_enc_kernel(const float* __restrict__ coords,
                        const int*   __restrict__ atypes,
                        const int*   __restrict__ rtypes,
                        const float* __restrict__ tpw,
                        const float* __restrict__ aemb,
                        const float* __restrict__ remb,
                        float* __restrict__ out)
{
    __shared__ float4 pts[NN];      // x, y, z, -n2/2
    __shared__ float  sW[8 * 32];

    const int tid  = threadIdx.x;
    const int lane = tid & 63;
    const int wv   = tid >> 6;
    const int bpb  = NN / NPB;
    const int batch    = blockIdx.x / bpb;
    const int nodeBase = (blockIdx.x % bpb) * NPB;

    const float* cb = coords + (size_t)batch * NN * 3;

    for (int p = tid; p < NN; p += BLOCK) {
        float x = cb[3*p], y = cb[3*p+1], z = cb[3*p+2];
        float nh = -0.5f * (x*x + y*y + z*z);
        pts[p] = make_float4(x, y, z, nh);
    }
    if (tid < 256) sW[tid] = tpw[tid];
    __syncthreads();

    const int iLoc = nodeBase + wv;
    const int gi   = batch * NN + iLoc;
    const float4 Pi = pts[iLoc];
    const float xi = Pi.x, yi = Pi.y, zi = Pi.z;

    // ---- phase 1: branchless per-lane top-2 on surrogate score (10 ops/cand) ----
    float b_sc = -BIGF, s_sc = -BIGF;
    int   b_idx = -1,   s_idx = -1;

    #pragma unroll 8
    for (int c = 0; c < NN / 64; ++c) {
        int j = lane + (c << 6);
        float4 P = pts[j];
        float d = fmaf(P.x, xi, fmaf(P.y, yi, fmaf(P.z, zi, P.w)));
        bool gt_b = d > b_sc;
        bool gt_s = d > s_sc;
        float m1 = fminf(d, b_sc);            // loser of (d, best)
        s_sc  = fmaxf(s_sc, m1);              // med3 pattern
        s_idx = gt_b ? b_idx : (gt_s ? j : s_idx);
        b_sc  = fmaxf(b_sc, d);
        b_idx = gt_b ? j : b_idx;
    }

    // self wins its column (score max at d2=0): demote it
    if (lane == (iLoc & 63) && b_idx == iLoc) {
        b_sc = s_sc; b_idx = s_idx; s_sc = -BIGF; s_idx = -1;
    }

    // ---- phase 2: 16 extractions with lazy replay ----
    unsigned long long used = 0ull;   // bit t => candidate (lane + 64t) consumed
    int selIdx = 0;

    #pragma unroll 1
    for (int r = 0; r < KNEI; ++r) {
        float m; int midx, w;
        wave_argmax(b_sc, b_idx, m, midx, w);
        if ((lane >> 2) == r) selIdx = midx;          // 4-lane team r owns edge r

        bool needReplay = (__builtin_amdgcn_readlane(s_idx, w) == -1);
        if (lane == w) {                               // promote second -> best
            used |= 1ull << (b_idx >> 6);
            b_sc = s_sc;  b_idx = s_idx;
            s_sc = -BIGF; s_idx = -1;
        }
        if (needReplay) {                              // uniform rare branch:
            int j2 = w + (lane << 6);                  // wave rescans lane w's 64
            float scr = score_calc(pts[j2], xi, yi, zi, j2, iLoc);
            unsigned lo = (unsigned)__builtin_amdgcn_readlane((int)(used & 0xffffffffull), w);
            unsigned hi = (unsigned)__builtin_amdgcn_readlane((int)(used >> 32), w);
            unsigned long long uw = ((unsigned long long)hi << 32) | lo;
            if ((uw >> lane) & 1ull) scr = -BIGF;
            float m2; int i2, w2;
            wave_argmax(scr, j2, m2, i2, w2);
            if (lane == w) { b_sc = m2; b_idx = i2; }  // refill best only
        }
    }

    // ---- epilogue: 4 lanes per edge, 6 S-components each ----
    const int g = lane & 3;                // component group within the team
    float4 P = pts[selIdx];
    float rx = P.x - xi, ry = P.y - yi, rz = P.z - zi;   // sender - receiver
    float dist = sqrtf(rx*rx + ry*ry + rz*rz);
    float inv  = 1.0f / (dist + 1e-8f);
    float hx = rx * inv, hy = ry * inv, hz = rz * inv;
    float cu = fminf(dist / 10.0f, 1.0f);
    float gg[8], ssum = 0.0f;
    #pragma unroll
    for (int v = 0; v < 8; ++v) {
        float d = cu - (float)v * (1.0f / 7.0f);
        gg[v] = expf(d * d * -32.0f);
        ssum += gg[v];
    }
    float is = 1.0f / ssum;
    float rb0 = gg[2*g] * is, rb1 = gg[2*g+1] * is;
    float S[6] = { rb0*hx, rb0*hy, rb0*hz, rb1*hx, rb1*hy, rb1*hz };

    #pragma unroll
    for (int off = 4; off <= 32; off <<= 1) {
        #pragma unroll
        for (int t = 0; t < 6; ++t) S[t] += __shfl_xor(S[t], off);
    }
    // lanes 0..3 hold the 24 edge-summed components; publish uniformly
    float sg[24];
    #pragma unroll
    for (int g0 = 0; g0 < 4; ++g0) {
        #pragma unroll
        for (int t = 0; t < 6; ++t)
            sg[6*g0 + t] = __int_as_float(
                __builtin_amdgcn_readlane(__float_as_int(S[t]), g0));
    }

    float* onode = out + (size_t)gi * 464;
    float4* o4 = (float4*)onode;
    const float4 z4 = make_float4(0.f, 0.f, 0.f, 0.f);
    if (lane < 16)       o4[lane] = z4;          // ch 0..63
    else if (lane < 36)  o4[lane + 24] = z4;     // ch 160..239

    const float scale = 0.036084391824351613f;   // 1/(16*sqrt(3))
    if (lane < 32) {
        float a0 = 0.f, a1 = 0.f, a2 = 0.f;
        #pragma unroll
        for (int v = 0; v < 8; ++v) {
            float wf = sW[32*v + lane];
            a0 = fmaf(wf, sg[3*v],   a0);
            a1 = fmaf(wf, sg[3*v+1], a1);
            a2 = fmaf(wf, sg[3*v+2], a2);
        }
        onode[64 + 3*lane]     = a0 * scale;
        onode[64 + 3*lane + 1] = a1 * scale;
        onode[64 + 3*lane + 2] = a2 * scale;
    }

    const int at = atypes[gi];
    const int rt = rtypes[gi];
    if (lane < 56) {
        float4 v = (lane < 28)
            ? ((const float4*)(aemb + 112*at))[lane]
            : ((const float4*)(remb + 112*rt))[lane - 28];
        o4[60 + lane] = v;
    }
}

extern "C" void kernel_launch(void* const* d_in, const int* in_sizes, int n_in,
                              void* d_out, int out_size, void* d_ws, size_t ws_size,
                              hipStream_t stream)
{
    const float* coords = (const float*)d_in[0];
    const int*   at     = (const int*)  d_in[1];
    const int*   rt     = (const int*)  d_in[2];
    const float* tpw    = (const float*)d_in[3];
    const float* ae     = (const float*)d_in[4];
    const float* re     = (const float*)d_in[5];
    float* out = (float*)d_out;

    const int B = in_sizes[1] / NN;                  // 8
    dim3 grid(B * (NN / NPB));
    protein_enc_kernel<<<grid, BLOCK, 0, stream>>>(coords, at, rt, tpw, ae, re, out);
}